// Round 17
// baseline (782.613 us; speedup 1.0000x reference)
//
#include <hip/hip_runtime.h>

#define NN 100000
#define NE 1600000
#define HD 128
#define NL 3
#define NG 1024
#define CAP 64                               // max in-degree bucket capacity

typedef __attribute__((ext_vector_type(8))) short short8v;   // 8 bf16 = 4 VGPRs
typedef __attribute__((ext_vector_type(4))) float float4v;

__device__ inline unsigned short f2bf(float f) {             // RNE f32->bf16
    unsigned int u = __float_as_uint(f);
    u += 0x7fffu + ((u >> 16) & 1u);
    return (unsigned short)(u >> 16);
}
__device__ inline float bf2f(unsigned short h) {
    return __uint_as_float(((unsigned int)h) << 16);
}
__device__ inline float2 bfpair(unsigned int u) {            // [lo16=feat0, hi16=feat1]
    float2 r;
    r.x = __uint_as_float(u << 16);
    r.y = __uint_as_float(u & 0xffff0000u);
    return r;
}

// ---------------- init: zero cnt, init graph bounds ----------------
__global__ void k_init(int* cnt, int* gstart, int* gend) {
    int i = blockIdx.x * blockDim.x + threadIdx.x;
    if (i < NN) cnt[i] = 0;
    if (i < NG) { gstart[i] = 0x7fffffff; gend[i] = 0; }
}

// ------- single-pass CSR build (frozen: at random-scatter line floor ~128 us) -------
__global__ void k_fillcap(const int* __restrict__ src, const int* __restrict__ dst,
                          int* __restrict__ cnt, int* __restrict__ srcT) {
    int e = blockIdx.x * blockDim.x + threadIdx.x;
    const int H = NE / 2;
    if (e < H) {
        int s0 = src[e],     d0 = dst[e];
        int s1 = src[e + H], d1 = dst[e + H];
        int p0 = atomicAdd(&cnt[d0], 1);
        int p1 = atomicAdd(&cnt[d1], 1);
        if (p0 < CAP) srcT[d0 * CAP + p0] = s0;
        if (p1 < CAP) srcT[d1 * CAP + p1] = s1;
    }
}

// ---------------- dinv from final counts ----------------
__global__ void k_deg(const int* __restrict__ cnt, float* __restrict__ dinv) {
    int i = blockIdx.x * blockDim.x + threadIdx.x;
    if (i < NN) dinv[i] = rsqrtf((float)(cnt[i] + 1));   // +1 self loop
}

// ------- W prep: split fp32 W into transposed bf16 hi/lo, once per layer -------
__global__ void k_wprep(const float* __restrict__ Ws,
                        unsigned short* __restrict__ WhT,
                        unsigned short* __restrict__ WlT) {
    int i = blockIdx.x * blockDim.x + threadIdx.x;   // over NL*HD*HD, k fastest
    if (i < NL * HD * HD) {
        int k = i & (HD - 1);
        int n = (i >> 7) & (HD - 1);
        int l = i >> 14;
        float f = Ws[(size_t)l * HD * HD + (size_t)k * HD + n];
        unsigned short hi = f2bf(f);
        WhT[i] = hi;
        WlT[i] = f2bf(f - bf2f(hi));
    }
}

// ======= fused layer: Hout = relu?( agg(Hprev) @ (Whi+Wlo) + bias ) =======
// agg(h)[n] = dn*( sum_e dinv[s]*h[s] + dn*h[n] ),  h = emb[x[.]] when L0.
// Phase 1: 4 waves aggregate 16 nodes each -> Ah LDS (bf16).
// Phase 2: MFMA 64x128 tile @ W (hi/lo split), bias/relu epilogue.
template<int L0>
__global__ __launch_bounds__(256) void k_fused(const unsigned short* __restrict__ Hprev,
                                               const int* __restrict__ xidx,
                                               const float* __restrict__ emb,
                                               const int* __restrict__ cnt,
                                               const int* __restrict__ srcT,
                                               const float* __restrict__ dinv,
                                               const unsigned short* __restrict__ WhT,
                                               const unsigned short* __restrict__ WlT,
                                               const float* __restrict__ bias,
                                               unsigned short* __restrict__ Hout,
                                               int relu) {
    __shared__ unsigned short Ah[64][136];   // [row][k]; 272B row stride (16B-aligned)
    __shared__ unsigned short Wh[128][40];   // [n][k]
    __shared__ unsigned short Wl[128][40];   // [n][k]
    int n0 = blockIdx.x * 64;
    int t  = threadIdx.x;
    int lane = t & 63, wv = t >> 6;

    // ---- phase 1: aggregation (wave wv owns nodes wv*16 .. wv*16+15) ----
    for (int i = 0; i < 16; ++i) {
        int node = wv * 16 + i;
        int n = n0 + node;
        float2 acc = make_float2(0.f, 0.f);
        if (n < NN) {
            float dn = dinv[n];
            float2 hv;
            if (L0) {
                int xv = xidx[n];
                hv = *(const float2*)(emb + (size_t)xv * HD + lane * 2);
            } else {
                hv = bfpair(*(const unsigned int*)(Hprev + (size_t)n * HD + lane * 2));
            }
            acc.x = dn * hv.x;               // self-loop inside dn-scaled sum
            acc.y = dn * hv.y;
            int end = cnt[n];
            if (end > CAP) end = CAP;
            const int* row = srcT + n * CAP;
            int idx = 0;
            if (end >= 8) {                  // 2-deep pipeline, batches of 8 (r15 structure)
                float wA[8]; float2 uA[8];
                {
                    int s[8];
#pragma unroll
                    for (int q = 0; q < 8; ++q) s[q] = row[q];
#pragma unroll
                    for (int q = 0; q < 8; ++q) wA[q] = dinv[s[q]];
                    if (L0) {
                        int xv2[8];
#pragma unroll
                        for (int q = 0; q < 8; ++q) xv2[q] = xidx[s[q]];
#pragma unroll
                        for (int q = 0; q < 8; ++q)
                            uA[q] = *(const float2*)(emb + (size_t)xv2[q] * HD + lane * 2);
                    } else {
#pragma unroll
                        for (int q = 0; q < 8; ++q)
                            uA[q] = bfpair(*(const unsigned int*)(Hprev + (size_t)s[q] * HD + lane * 2));
                    }
                }
                int next = 8;
                while (next + 8 <= end) {
                    float wB[8]; float2 uB[8];
                    {
                        int s[8];
#pragma unroll
                        for (int q = 0; q < 8; ++q) s[q] = row[next + q];
#pragma unroll
                        for (int q = 0; q < 8; ++q) wB[q] = dinv[s[q]];
                        if (L0) {
                            int xv2[8];
#pragma unroll
                            for (int q = 0; q < 8; ++q) xv2[q] = xidx[s[q]];
#pragma unroll
                            for (int q = 0; q < 8; ++q)
                                uB[q] = *(const float2*)(emb + (size_t)xv2[q] * HD + lane * 2);
                        } else {
#pragma unroll
                            for (int q = 0; q < 8; ++q)
                                uB[q] = bfpair(*(const unsigned int*)(Hprev + (size_t)s[q] * HD + lane * 2));
                        }
                    }
#pragma unroll
                    for (int q = 0; q < 8; ++q) {
                        acc.x = fmaf(wA[q], uA[q].x, acc.x);
                        acc.y = fmaf(wA[q], uA[q].y, acc.y);
                    }
#pragma unroll
                    for (int q = 0; q < 8; ++q) { wA[q] = wB[q]; uA[q] = uB[q]; }
                    next += 8;
                }
#pragma unroll
                for (int q = 0; q < 8; ++q) {
                    acc.x = fmaf(wA[q], uA[q].x, acc.x);
                    acc.y = fmaf(wA[q], uA[q].y, acc.y);
                }
                idx = next;
            }
            for (; idx < end; ++idx) {
                int s   = row[idx];
                float w = dinv[s];
                float2 v;
                if (L0) v = *(const float2*)(emb + (size_t)xidx[s] * HD + lane * 2);
                else    v = bfpair(*(const unsigned int*)(Hprev + (size_t)s * HD + lane * 2));
                acc.x = fmaf(w, v.x, acc.x);
                acc.y = fmaf(w, v.y, acc.y);
            }
            acc.x *= dn;
            acc.y *= dn;
        }
        unsigned int o = (unsigned)f2bf(acc.x) | ((unsigned)f2bf(acc.y) << 16);
        *(unsigned int*)&Ah[node][lane * 2] = o;
    }
    __syncthreads();

    // ---- phase 2: GEMM Ah @ (Wh + Wl), bias/relu, write Hout ----
    int lm = lane & 15, lk = lane >> 4;
    float4v accv[8];
#pragma unroll
    for (int i = 0; i < 8; ++i) accv[i] = (float4v)0.f;
    for (int kc = 0; kc < 4; ++kc) {
        int k0 = kc * 32;
#pragma unroll
        for (int it = 0; it < 2; ++it) {
            int lin = t + it * 256;          // 512 (n, seg) pairs
            int nn = lin >> 2, seg = lin & 3;
            *(uint4*)&Wh[nn][seg * 8] =
                *(const uint4*)(WhT + (size_t)nn * HD + k0 + seg * 8);
            *(uint4*)&Wl[nn][seg * 8] =
                *(const uint4*)(WlT + (size_t)nn * HD + k0 + seg * 8);
        }
        __syncthreads();
        short8v a = *(const short8v*)&Ah[wv * 16 + lm][k0 + lk * 8];
#pragma unroll
        for (int nt = 0; nt < 8; ++nt) {
            short8v bh = *(const short8v*)&Wh[nt * 16 + lm][lk * 8];
            short8v bl = *(const short8v*)&Wl[nt * 16 + lm][lk * 8];
            accv[nt] = __builtin_amdgcn_mfma_f32_16x16x32_bf16(a, bh, accv[nt], 0, 0, 0);
            accv[nt] = __builtin_amdgcn_mfma_f32_16x16x32_bf16(a, bl, accv[nt], 0, 0, 0);
        }
        __syncthreads();
    }
    // epilogue: C/D layout col = lane&15, row = (lane>>4)*4 + reg  [m89]
    int rbase = n0 + wv * 16 + (lane >> 4) * 4;
#pragma unroll
    for (int nt = 0; nt < 8; ++nt) {
        int col = nt * 16 + lm;
        float bb = bias[col];
#pragma unroll
        for (int rg = 0; rg < 4; ++rg) {
            int r = rbase + rg;
            if (r < NN) {
                float v = accv[nt][rg] + bb;
                if (relu) v = fmaxf(v, 0.f);
                Hout[(size_t)r * HD + col] = f2bf(v);
            }
        }
    }
}

// ---------------- graph bounds (batch is sorted) ----------------
__global__ void k_bounds(const int* __restrict__ batch, int* __restrict__ gstart,
                         int* __restrict__ gend) {
    int i = blockIdx.x * blockDim.x + threadIdx.x;
    if (i < NN) {
        int g = batch[i];
        atomicMin(&gstart[g], i);
        atomicMax(&gend[g], i + 1);
    }
}

// ------- mean pool per graph: 8 independent partial sums (8 loads in flight) -------
__global__ __launch_bounds__(128) void k_pool(const unsigned short* __restrict__ A,
                                              const int* __restrict__ gstart,
                                              const int* __restrict__ gend,
                                              float* __restrict__ out) {
    int g = blockIdx.x;
    int t = threadIdx.x;
    int s = gstart[g], e = gend[g];
    float acc[8];
#pragma unroll
    for (int q = 0; q < 8; ++q) acc[q] = 0.f;
    int cntn = 0;
    if (s < e) {
        cntn = e - s;
        int n = s;
        for (; n + 8 <= e; n += 8) {
#pragma unroll
            for (int q = 0; q < 8; ++q)
                acc[q] += bf2f(A[(size_t)(n + q) * HD + t]);
        }
        for (; n < e; ++n) acc[0] += bf2f(A[(size_t)n * HD + t]);
    }
    float tot = ((acc[0] + acc[1]) + (acc[2] + acc[3])) +
                ((acc[4] + acc[5]) + (acc[6] + acc[7]));
    out[(size_t)g * HD + t] = tot / fmaxf((float)cntn, 1.f);
}

extern "C" void kernel_launch(void* const* d_in, const int* in_sizes, int n_in,
                              void* d_out, int out_size, void* d_ws, size_t ws_size,
                              hipStream_t stream) {
    const int*   x     = (const int*)d_in[0];
    const int*   ei    = (const int*)d_in[1];
    const int*   batch = (const int*)d_in[2];
    const float* emb   = (const float*)d_in[3];
    const float* Ws    = (const float*)d_in[4];
    const float* bs    = (const float*)d_in[5];
    float* out = (float*)d_out;

    const int* srcE = ei;
    const int* dstE = ei + NE;

    char* ws = (char*)d_ws;
    size_t off = 0;
    auto alloc = [&](size_t bytes) {
        size_t o = off;
        off = (off + bytes + 255) & ~(size_t)255;
        return o;
    };
    unsigned short* hA  = (unsigned short*)(ws + alloc((size_t)NN * HD * 2));
    unsigned short* hB  = (unsigned short*)(ws + alloc((size_t)NN * HD * 2));
    unsigned short* WhT = (unsigned short*)(ws + alloc((size_t)NL * HD * HD * 2));
    unsigned short* WlT = (unsigned short*)(ws + alloc((size_t)NL * HD * HD * 2));
    float* dinv   = (float*)(ws + alloc((size_t)NN * 4));
    int*   cnt    = (int*)  (ws + alloc((size_t)NN * 4));
    int*   srcT   = (int*)  (ws + alloc((size_t)NN * CAP * 4));
    int*   gstart = (int*)  (ws + alloc((size_t)NG * 4));
    int*   gend   = (int*)  (ws + alloc((size_t)NG * 4));
    (void)ws_size; (void)in_sizes; (void)n_in; (void)out_size;

    k_init<<<(NN + 255) / 256, 256, 0, stream>>>(cnt, gstart, gend);
    k_fillcap<<<(NE / 2 + 255) / 256, 256, 0, stream>>>(srcE, dstE, cnt, srcT);
    k_deg<<<(NN + 255) / 256, 256, 0, stream>>>(cnt, dinv);
    k_wprep<<<(NL * HD * HD + 255) / 256, 256, 0, stream>>>(Ws, WhT, WlT);

    const int GGRID = (NN + 63) / 64;
    // layer 0: aggregate emb[x[.]] (L1/L2-resident), GEMM -> hA
    k_fused<1><<<GGRID, 256, 0, stream>>>(nullptr, x, emb, cnt, srcT, dinv,
                                          WhT, WlT, bs, hA, 1);
    // layer 1: hA -> hB
    k_fused<0><<<GGRID, 256, 0, stream>>>(hA, x, emb, cnt, srcT, dinv,
                                          WhT + (size_t)1 * HD * HD, WlT + (size_t)1 * HD * HD,
                                          bs + 1 * HD, hB, 1);
    // layer 2: hB -> hA (no relu)
    k_fused<0><<<GGRID, 256, 0, stream>>>(hB, x, emb, cnt, srcT, dinv,
                                          WhT + (size_t)2 * HD * HD, WlT + (size_t)2 * HD * HD,
                                          bs + 2 * HD, hA, 0);

    k_bounds<<<(NN + 255) / 256, 256, 0, stream>>>(batch, gstart, gend);
    k_pool<<<NG, 128, 0, stream>>>(hA, gstart, gend, out);
}

// Round 18
// 424.121 us; speedup vs baseline: 1.8453x; 1.8453x over previous
//
#include <hip/hip_runtime.h>

#define NN 100000
#define NE 1600000
#define HD 128
#define NL 3
#define NG 1024
#define CAP 64                               // max in-degree bucket capacity
#define NPARTS 8                             // dst partitions == XCD count
#define PSIZE ((NN + NPARTS - 1) / NPARTS)   // 12500 nodes/partition

typedef __attribute__((ext_vector_type(8))) short short8v;   // 8 bf16 = 4 VGPRs
typedef __attribute__((ext_vector_type(4))) float float4v;

__device__ inline unsigned short f2bf(float f) {             // RNE f32->bf16
    unsigned int u = __float_as_uint(f);
    u += 0x7fffu + ((u >> 16) & 1u);
    return (unsigned short)(u >> 16);
}
__device__ inline float bf2f(unsigned short h) {
    return __uint_as_float(((unsigned int)h) << 16);
}
__device__ inline float2 bfpair(unsigned int u) {            // [lo16=feat0, hi16=feat1]
    float2 r;
    r.x = __uint_as_float(u << 16);
    r.y = __uint_as_float(u & 0xffff0000u);
    return r;
}

// ---------------- init: zero cnt, init graph bounds ----------------
__global__ void k_init(int* cnt, int* gstart, int* gend) {
    int i = blockIdx.x * blockDim.x + threadIdx.x;
    if (i < NN) cnt[i] = 0;
    if (i < NG) { gstart[i] = 0x7fffffff; gend[i] = 0; }
}

// ------- XCD-partitioned CSR build: block bx handles dst partition bx&7. -------
// Round-robin blockIdx->XCD means partition p's 3.2MB srcT slice is touched by
// one XCD only -> dirty lines stay in its 4MB L2, evicted ~once (WRITE 96->~15MB).
// Cost: each edge read NPARTS x (streaming, ~16us).
__global__ void k_fillcap(const int* __restrict__ src, const int* __restrict__ dst,
                          int* __restrict__ cnt, int* __restrict__ srcT) {
    int part  = blockIdx.x & (NPARTS - 1);
    int chunk = blockIdx.x >> 3;
    int e = chunk * 256 + threadIdx.x;
    if (e < NE) {
        int d = dst[e];
        if (d / PSIZE == part) {
            int s = src[e];
            int pos = atomicAdd(&cnt[d], 1);
            if (pos < CAP) srcT[d * CAP + pos] = s;   // Poisson(16): pos>=64 never
        }
    }
}

// ---------------- dinv from final counts ----------------
__global__ void k_deg(const int* __restrict__ cnt, float* __restrict__ dinv) {
    int i = blockIdx.x * blockDim.x + threadIdx.x;
    if (i < NN) dinv[i] = rsqrtf((float)(cnt[i] + 1));   // +1 self loop
}

// ------- W prep: split fp32 W into transposed bf16 hi/lo, once per layer -------
__global__ void k_wprep(const float* __restrict__ Ws,
                        unsigned short* __restrict__ WhT,
                        unsigned short* __restrict__ WlT) {
    int i = blockIdx.x * blockDim.x + threadIdx.x;   // over NL*HD*HD, k fastest
    if (i < NL * HD * HD) {
        int k = i & (HD - 1);
        int n = (i >> 7) & (HD - 1);
        int l = i >> 14;
        float f = Ws[(size_t)l * HD * HD + (size_t)k * HD + n];
        unsigned short hi = f2bf(f);
        WhT[i] = hi;
        WlT[i] = f2bf(f - bf2f(hi));
    }
}

// ------- MFMA GEMM: B(bf16) = A(bf16) @ (Whi + Wlo); layer-0 A = emb[x] -------
template<int WITH_EMB>
__global__ __launch_bounds__(256) void k_gemm_mfma(const unsigned short* __restrict__ A,
                                                   const int* __restrict__ xidx,
                                                   const float* __restrict__ emb,
                                                   const unsigned short* __restrict__ WhT,
                                                   const unsigned short* __restrict__ WlT,
                                                   unsigned short* __restrict__ B) {
    __shared__ unsigned short Ah[64][40];    // [row][k] pad 32->40
    __shared__ unsigned short Wh[128][40];   // [n][k]
    __shared__ unsigned short Wl[128][40];   // [n][k]
    __shared__ int xs[64];
    int n0 = blockIdx.x * 64;
    int t  = threadIdx.x;
    if (WITH_EMB && t < 64) xs[t] = (n0 + t < NN) ? xidx[n0 + t] : 0;
    int lane = t & 63, wv = t >> 6;
    int lm = lane & 15, lk = lane >> 4;
    float4v acc[8];
#pragma unroll
    for (int i = 0; i < 8; ++i) acc[i] = (float4v)0.f;

    for (int kc = 0; kc < 4; ++kc) {
        int k0 = kc * 32;
        __syncthreads();
        {
            int row = t >> 2, seg = t & 3;
            int r = n0 + row;
            uint4 u = make_uint4(0u, 0u, 0u, 0u);
            if (r < NN) {
                if (WITH_EMB) {
                    const float* p = emb + (size_t)xs[row] * HD + k0 + seg * 8;
                    float4 f0 = *(const float4*)p;
                    float4 f1 = *(const float4*)(p + 4);
                    u.x = (unsigned)f2bf(f0.x) | ((unsigned)f2bf(f0.y) << 16);
                    u.y = (unsigned)f2bf(f0.z) | ((unsigned)f2bf(f0.w) << 16);
                    u.z = (unsigned)f2bf(f1.x) | ((unsigned)f2bf(f1.y) << 16);
                    u.w = (unsigned)f2bf(f1.z) | ((unsigned)f2bf(f1.w) << 16);
                } else {
                    u = *(const uint4*)(A + (size_t)r * HD + k0 + seg * 8);
                }
            }
            *(uint4*)&Ah[row][seg * 8] = u;
        }
#pragma unroll
        for (int it = 0; it < 2; ++it) {
            int lin = t + it * 256;          // over 512 (n, seg) pairs
            int n = lin >> 2, seg = lin & 3;
            *(uint4*)&Wh[n][seg * 8] =
                *(const uint4*)(WhT + (size_t)n * HD + k0 + seg * 8);
            *(uint4*)&Wl[n][seg * 8] =
                *(const uint4*)(WlT + (size_t)n * HD + k0 + seg * 8);
        }
        __syncthreads();
        short8v a = *(const short8v*)&Ah[wv * 16 + lm][lk * 8];
#pragma unroll
        for (int nt = 0; nt < 8; ++nt) {
            short8v bh = *(const short8v*)&Wh[nt * 16 + lm][lk * 8];
            short8v bl = *(const short8v*)&Wl[nt * 16 + lm][lk * 8];
            acc[nt] = __builtin_amdgcn_mfma_f32_16x16x32_bf16(a, bh, acc[nt], 0, 0, 0);
            acc[nt] = __builtin_amdgcn_mfma_f32_16x16x32_bf16(a, bl, acc[nt], 0, 0, 0);
        }
    }
    int rbase = n0 + wv * 16 + (lane >> 4) * 4;
#pragma unroll
    for (int nt = 0; nt < 8; ++nt) {
        int col = nt * 16 + lm;
#pragma unroll
        for (int rg = 0; rg < 4; ++rg) {
            int r = rbase + rg;
            if (r < NN) B[(size_t)r * HD + col] = f2bf(acc[nt][rg]);
        }
    }
}

// ------- pull-gather, 2-deep pipelined batches of 8 (16 rows in flight) — r15 -------
__global__ __launch_bounds__(256) void k_gather(const unsigned short* __restrict__ B,
                                                const int* __restrict__ cnt,
                                                const int* __restrict__ srcT,
                                                const float* __restrict__ dinv,
                                                const float* __restrict__ bias,
                                                unsigned short* __restrict__ A, int relu) {
    int wid  = (blockIdx.x * blockDim.x + threadIdx.x) >> 6;  // wave per node
    int lane = threadIdx.x & 63;
    if (wid >= NN) return;
    int n = wid;
    float dn = dinv[n];
    float2 b0 = bfpair(*(const unsigned int*)(B + (size_t)n * HD + lane * 2));
    float2 acc;
    acc.x = dn * b0.x;        // self-loop inside dn-scaled sum
    acc.y = dn * b0.y;
    int end = cnt[n];
    if (end > CAP) end = CAP;
    const int* row = srcT + n * CAP;
    int idx = 0;
    if (end >= 8) {
        float wA[8]; unsigned int uA[8];
        {
            int s[8];
#pragma unroll
            for (int q = 0; q < 8; ++q) s[q] = row[q];
#pragma unroll
            for (int q = 0; q < 8; ++q) wA[q] = dinv[s[q]];
#pragma unroll
            for (int q = 0; q < 8; ++q)
                uA[q] = *(const unsigned int*)(B + (size_t)s[q] * HD + lane * 2);
        }
        int next = 8;
        while (next + 8 <= end) {
            float wB[8]; unsigned int uB[8];
            {
                int s[8];
#pragma unroll
                for (int q = 0; q < 8; ++q) s[q] = row[next + q];
#pragma unroll
                for (int q = 0; q < 8; ++q) wB[q] = dinv[s[q]];
#pragma unroll
                for (int q = 0; q < 8; ++q)            // issued while uA in flight
                    uB[q] = *(const unsigned int*)(B + (size_t)s[q] * HD + lane * 2);
            }
#pragma unroll
            for (int q = 0; q < 8; ++q) {              // consume A
                float2 v = bfpair(uA[q]);
                acc.x = fmaf(wA[q], v.x, acc.x);
                acc.y = fmaf(wA[q], v.y, acc.y);
            }
#pragma unroll
            for (int q = 0; q < 8; ++q) { wA[q] = wB[q]; uA[q] = uB[q]; }
            next += 8;
        }
#pragma unroll
        for (int q = 0; q < 8; ++q) {                  // consume final batch
            float2 v = bfpair(uA[q]);
            acc.x = fmaf(wA[q], v.x, acc.x);
            acc.y = fmaf(wA[q], v.y, acc.y);
        }
        idx = next;
    }
    for (; idx < end; ++idx) {
        int s   = row[idx];
        float w = dinv[s];
        float2 v = bfpair(*(const unsigned int*)(B + (size_t)s * HD + lane * 2));
        acc.x = fmaf(w, v.x, acc.x);
        acc.y = fmaf(w, v.y, acc.y);
    }
    float2 bb = ((const float2*)bias)[lane];
    acc.x = fmaf(dn, acc.x, bb.x);
    acc.y = fmaf(dn, acc.y, bb.y);
    if (relu) { acc.x = fmaxf(acc.x, 0.f); acc.y = fmaxf(acc.y, 0.f); }
    unsigned int o = (unsigned)f2bf(acc.x) | ((unsigned)f2bf(acc.y) << 16);
    *(unsigned int*)(A + (size_t)n * HD + lane * 2) = o;
}

// ---------------- graph bounds (batch is sorted) ----------------
__global__ void k_bounds(const int* __restrict__ batch, int* __restrict__ gstart,
                         int* __restrict__ gend) {
    int i = blockIdx.x * blockDim.x + threadIdx.x;
    if (i < NN) {
        int g = batch[i];
        atomicMin(&gstart[g], i);
        atomicMax(&gend[g], i + 1);
    }
}

// ------- mean pool per graph: 8 independent partial sums (8 loads in flight) -------
__global__ __launch_bounds__(128) void k_pool(const unsigned short* __restrict__ A,
                                              const int* __restrict__ gstart,
                                              const int* __restrict__ gend,
                                              float* __restrict__ out) {
    int g = blockIdx.x;
    int t = threadIdx.x;
    int s = gstart[g], e = gend[g];
    float acc[8];
#pragma unroll
    for (int q = 0; q < 8; ++q) acc[q] = 0.f;
    int cntn = 0;
    if (s < e) {
        cntn = e - s;
        int n = s;
        for (; n + 8 <= e; n += 8) {
#pragma unroll
            for (int q = 0; q < 8; ++q)
                acc[q] += bf2f(A[(size_t)(n + q) * HD + t]);
        }
        for (; n < e; ++n) acc[0] += bf2f(A[(size_t)n * HD + t]);
    }
    float tot = ((acc[0] + acc[1]) + (acc[2] + acc[3])) +
                ((acc[4] + acc[5]) + (acc[6] + acc[7]));
    out[(size_t)g * HD + t] = tot / fmaxf((float)cntn, 1.f);
}

extern "C" void kernel_launch(void* const* d_in, const int* in_sizes, int n_in,
                              void* d_out, int out_size, void* d_ws, size_t ws_size,
                              hipStream_t stream) {
    const int*   x     = (const int*)d_in[0];
    const int*   ei    = (const int*)d_in[1];
    const int*   batch = (const int*)d_in[2];
    const float* emb   = (const float*)d_in[3];
    const float* Ws    = (const float*)d_in[4];
    const float* bs    = (const float*)d_in[5];
    float* out = (float*)d_out;

    const int* srcE = ei;
    const int* dstE = ei + NE;

    char* ws = (char*)d_ws;
    size_t off = 0;
    auto alloc = [&](size_t bytes) {
        size_t o = off;
        off = (off + bytes + 255) & ~(size_t)255;
        return o;
    };
    unsigned short* hA  = (unsigned short*)(ws + alloc((size_t)NN * HD * 2));
    unsigned short* hB  = (unsigned short*)(ws + alloc((size_t)NN * HD * 2));
    unsigned short* WhT = (unsigned short*)(ws + alloc((size_t)NL * HD * HD * 2));
    unsigned short* WlT = (unsigned short*)(ws + alloc((size_t)NL * HD * HD * 2));
    float* dinv   = (float*)(ws + alloc((size_t)NN * 4));
    int*   cnt    = (int*)  (ws + alloc((size_t)NN * 4));
    int*   srcT   = (int*)  (ws + alloc((size_t)NN * CAP * 4));
    int*   gstart = (int*)  (ws + alloc((size_t)NG * 4));
    int*   gend   = (int*)  (ws + alloc((size_t)NG * 4));
    (void)ws_size; (void)in_sizes; (void)n_in; (void)out_size;

    k_init<<<(NN + 255) / 256, 256, 0, stream>>>(cnt, gstart, gend);
    {
        int chunks = (NE + 255) / 256;
        k_fillcap<<<chunks * NPARTS, 256, 0, stream>>>(srcE, dstE, cnt, srcT);
    }
    k_deg<<<(NN + 255) / 256, 256, 0, stream>>>(cnt, dinv);
    k_wprep<<<(NL * HD * HD + 255) / 256, 256, 0, stream>>>(Ws, WhT, WlT);

    const int GGRID = (NN + 63) / 64;
    for (int l = 0; l < NL; ++l) {
        size_t wo = (size_t)l * HD * HD;
        if (l == 0)
            k_gemm_mfma<1><<<GGRID, 256, 0, stream>>>(hA, x, emb, WhT + wo, WlT + wo, hB);
        else
            k_gemm_mfma<0><<<GGRID, 256, 0, stream>>>(hA, x, emb, WhT + wo, WlT + wo, hB);
        k_gather<<<(NN + 3) / 4, 256, 0, stream>>>(hB, cnt, srcT, dinv,
                                                   bs + (size_t)l * HD, hA,
                                                   (l < NL - 1) ? 1 : 0);
    }

    k_bounds<<<(NN + 255) / 256, 256, 0, stream>>>(batch, gstart, gend);
    k_pool<<<NG, 128, 0, stream>>>(hA, gstart, gend, out);
}

// Round 19
// 397.296 us; speedup vs baseline: 1.9698x; 1.0675x over previous
//
#include <hip/hip_runtime.h>

#define NN 100000
#define NE 1600000
#define HD 128
#define NL 3
#define NG 1024
#define CAP 64                               // max in-degree bucket capacity
#define NPARTS 8                             // dst partitions == XCD count
#define PSIZE ((NN + NPARTS - 1) / NPARTS)   // 12500 nodes/partition

typedef __attribute__((ext_vector_type(8))) short short8v;   // 8 bf16 = 4 VGPRs
typedef __attribute__((ext_vector_type(4))) float float4v;

__device__ inline unsigned short f2bf(float f) {             // RNE f32->bf16
    unsigned int u = __float_as_uint(f);
    u += 0x7fffu + ((u >> 16) & 1u);
    return (unsigned short)(u >> 16);
}
__device__ inline float bf2f(unsigned short h) {
    return __uint_as_float(((unsigned int)h) << 16);
}
__device__ inline float2 bfpair(unsigned int u) {            // [lo16=feat0, hi16=feat1]
    float2 r;
    r.x = __uint_as_float(u << 16);
    r.y = __uint_as_float(u & 0xffff0000u);
    return r;
}

// ---------------- init: zero cnt, init graph bounds ----------------
__global__ void k_init(int* cnt, int* gstart, int* gend) {
    int i = blockIdx.x * blockDim.x + threadIdx.x;
    if (i < NN) cnt[i] = 0;
    if (i < NG) { gstart[i] = 0x7fffffff; gend[i] = 0; }
}

// ------- XCD-partitioned CSR build (r18 measured 84 us) -------
__global__ void k_fillcap(const int* __restrict__ src, const int* __restrict__ dst,
                          int* __restrict__ cnt, int* __restrict__ srcT) {
    int part  = blockIdx.x & (NPARTS - 1);
    int chunk = blockIdx.x >> 3;
    int e = chunk * 256 + threadIdx.x;
    if (e < NE) {
        int d = dst[e];
        if (d / PSIZE == part) {
            int s = src[e];
            int pos = atomicAdd(&cnt[d], 1);
            if (pos < CAP) srcT[d * CAP + pos] = s;   // Poisson(16): pos>=64 never
        }
    }
}

// ---------------- dinv from final counts ----------------
__global__ void k_deg(const int* __restrict__ cnt, float* __restrict__ dinv) {
    int i = blockIdx.x * blockDim.x + threadIdx.x;
    if (i < NN) dinv[i] = rsqrtf((float)(cnt[i] + 1));   // +1 self loop
}

// ------- W prep: split fp32 W into transposed bf16 hi/lo, once per layer -------
__global__ void k_wprep(const float* __restrict__ Ws,
                        unsigned short* __restrict__ WhT,
                        unsigned short* __restrict__ WlT) {
    int i = blockIdx.x * blockDim.x + threadIdx.x;   // over NL*HD*HD, k fastest
    if (i < NL * HD * HD) {
        int k = i & (HD - 1);
        int n = (i >> 7) & (HD - 1);
        int l = i >> 14;
        float f = Ws[(size_t)l * HD * HD + (size_t)k * HD + n];
        unsigned short hi = f2bf(f);
        WhT[i] = hi;
        WlT[i] = f2bf(f - bf2f(hi));
    }
}

// ------- MFMA GEMM: B(bf16) = A(bf16) @ (Whi + Wlo); layer-0 A = emb[x] -------
template<int WITH_EMB>
__global__ __launch_bounds__(256) void k_gemm_mfma(const unsigned short* __restrict__ A,
                                                   const int* __restrict__ xidx,
                                                   const float* __restrict__ emb,
                                                   const unsigned short* __restrict__ WhT,
                                                   const unsigned short* __restrict__ WlT,
                                                   unsigned short* __restrict__ B) {
    __shared__ unsigned short Ah[64][40];    // [row][k] pad 32->40
    __shared__ unsigned short Wh[128][40];   // [n][k]
    __shared__ unsigned short Wl[128][40];   // [n][k]
    __shared__ int xs[64];
    int n0 = blockIdx.x * 64;
    int t  = threadIdx.x;
    if (WITH_EMB && t < 64) xs[t] = (n0 + t < NN) ? xidx[n0 + t] : 0;
    int lane = t & 63, wv = t >> 6;
    int lm = lane & 15, lk = lane >> 4;
    float4v acc[8];
#pragma unroll
    for (int i = 0; i < 8; ++i) acc[i] = (float4v)0.f;

    for (int kc = 0; kc < 4; ++kc) {
        int k0 = kc * 32;
        __syncthreads();
        {
            int row = t >> 2, seg = t & 3;
            int r = n0 + row;
            uint4 u = make_uint4(0u, 0u, 0u, 0u);
            if (r < NN) {
                if (WITH_EMB) {
                    const float* p = emb + (size_t)xs[row] * HD + k0 + seg * 8;
                    float4 f0 = *(const float4*)p;
                    float4 f1 = *(const float4*)(p + 4);
                    u.x = (unsigned)f2bf(f0.x) | ((unsigned)f2bf(f0.y) << 16);
                    u.y = (unsigned)f2bf(f0.z) | ((unsigned)f2bf(f0.w) << 16);
                    u.z = (unsigned)f2bf(f1.x) | ((unsigned)f2bf(f1.y) << 16);
                    u.w = (unsigned)f2bf(f1.z) | ((unsigned)f2bf(f1.w) << 16);
                } else {
                    u = *(const uint4*)(A + (size_t)r * HD + k0 + seg * 8);
                }
            }
            *(uint4*)&Ah[row][seg * 8] = u;
        }
#pragma unroll
        for (int it = 0; it < 2; ++it) {
            int lin = t + it * 256;          // over 512 (n, seg) pairs
            int n = lin >> 2, seg = lin & 3;
            *(uint4*)&Wh[n][seg * 8] =
                *(const uint4*)(WhT + (size_t)n * HD + k0 + seg * 8);
            *(uint4*)&Wl[n][seg * 8] =
                *(const uint4*)(WlT + (size_t)n * HD + k0 + seg * 8);
        }
        __syncthreads();
        short8v a = *(const short8v*)&Ah[wv * 16 + lm][lk * 8];
#pragma unroll
        for (int nt = 0; nt < 8; ++nt) {
            short8v bh = *(const short8v*)&Wh[nt * 16 + lm][lk * 8];
            short8v bl = *(const short8v*)&Wl[nt * 16 + lm][lk * 8];
            acc[nt] = __builtin_amdgcn_mfma_f32_16x16x32_bf16(a, bh, acc[nt], 0, 0, 0);
            acc[nt] = __builtin_amdgcn_mfma_f32_16x16x32_bf16(a, bl, acc[nt], 0, 0, 0);
        }
    }
    int rbase = n0 + wv * 16 + (lane >> 4) * 4;
#pragma unroll
    for (int nt = 0; nt < 8; ++nt) {
        int col = nt * 16 + lm;
#pragma unroll
        for (int rg = 0; rg < 4; ++rg) {
            int r = rbase + rg;
            if (r < NN) B[(size_t)r * HD + col] = f2bf(acc[nt][rg]);
        }
    }
}

// ------- pull-gather, pair-packed: 2 edges per load instr, 16 edges in flight -------
// lane = (half, fl): half = lane>>5 handles even/odd edges; fl = lane&31 owns
// features fl*4..fl*4+3 (8B per row). Batch = 4 slots = 8 edges, 2-deep pipeline.
__global__ __launch_bounds__(256) void k_gather(const unsigned short* __restrict__ B,
                                                const int* __restrict__ cnt,
                                                const int* __restrict__ srcT,
                                                const float* __restrict__ dinv,
                                                const float* __restrict__ bias,
                                                unsigned short* __restrict__ A, int relu) {
    int wid  = (blockIdx.x * blockDim.x + threadIdx.x) >> 6;  // wave per node
    int lane = threadIdx.x & 63;
    if (wid >= NN) return;
    int half = lane >> 5;
    int fl   = lane & 31;
    int n = wid;
    float dn = dinv[n];
    float4 acc;
    {   // self-loop: half 0 carries weight dn, half 1 zero (summed in combine)
        uint2 su = *(const uint2*)(B + (size_t)n * HD + fl * 4);
        float2 p0 = bfpair(su.x), p1 = bfpair(su.y);
        float ws = half ? 0.f : dn;
        acc.x = ws * p0.x; acc.y = ws * p0.y;
        acc.z = ws * p1.x; acc.w = ws * p1.y;
    }
    int end = cnt[n];
    if (end > CAP) end = CAP;
    const int* row = srcT + n * CAP;
    int idx = 0;
    if (end >= 8) {
        float wA[4]; uint2 uA[4];
        {
            int s[4];
#pragma unroll
            for (int q = 0; q < 4; ++q) s[q] = row[2 * q + half];
#pragma unroll
            for (int q = 0; q < 4; ++q) wA[q] = dinv[s[q]];
#pragma unroll
            for (int q = 0; q < 4; ++q)
                uA[q] = *(const uint2*)(B + (size_t)s[q] * HD + fl * 4);
        }
        int next = 8;
        while (next + 8 <= end) {
            float wB[4]; uint2 uB[4];
            {
                int s[4];
#pragma unroll
                for (int q = 0; q < 4; ++q) s[q] = row[next + 2 * q + half];
#pragma unroll
                for (int q = 0; q < 4; ++q) wB[q] = dinv[s[q]];
#pragma unroll
                for (int q = 0; q < 4; ++q)            // issued while uA in flight
                    uB[q] = *(const uint2*)(B + (size_t)s[q] * HD + fl * 4);
            }
#pragma unroll
            for (int q = 0; q < 4; ++q) {              // consume A
                float2 p0 = bfpair(uA[q].x), p1 = bfpair(uA[q].y);
                acc.x = fmaf(wA[q], p0.x, acc.x); acc.y = fmaf(wA[q], p0.y, acc.y);
                acc.z = fmaf(wA[q], p1.x, acc.z); acc.w = fmaf(wA[q], p1.y, acc.w);
            }
#pragma unroll
            for (int q = 0; q < 4; ++q) { wA[q] = wB[q]; uA[q] = uB[q]; }
            next += 8;
        }
#pragma unroll
        for (int q = 0; q < 4; ++q) {                  // consume final batch
            float2 p0 = bfpair(uA[q].x), p1 = bfpair(uA[q].y);
            acc.x = fmaf(wA[q], p0.x, acc.x); acc.y = fmaf(wA[q], p0.y, acc.y);
            acc.z = fmaf(wA[q], p1.x, acc.z); acc.w = fmaf(wA[q], p1.y, acc.w);
        }
        idx = next;
    }
    for (; idx + 2 <= end; idx += 2) {                 // pair tail (2 edges/iter)
        int s   = row[idx + half];
        float w = dinv[s];
        uint2 u = *(const uint2*)(B + (size_t)s * HD + fl * 4);
        float2 p0 = bfpair(u.x), p1 = bfpair(u.y);
        acc.x = fmaf(w, p0.x, acc.x); acc.y = fmaf(w, p0.y, acc.y);
        acc.z = fmaf(w, p1.x, acc.z); acc.w = fmaf(w, p1.y, acc.w);
    }
    if (idx < end) {                                   // odd edge: half1 w=0, same row
        int s   = row[idx];
        float w = half ? 0.f : dinv[s];
        uint2 u = *(const uint2*)(B + (size_t)s * HD + fl * 4);
        float2 p0 = bfpair(u.x), p1 = bfpair(u.y);
        acc.x = fmaf(w, p0.x, acc.x); acc.y = fmaf(w, p0.y, acc.y);
        acc.z = fmaf(w, p1.x, acc.z); acc.w = fmaf(w, p1.y, acc.w);
    }
    // combine halves
    acc.x += __shfl_xor(acc.x, 32);
    acc.y += __shfl_xor(acc.y, 32);
    acc.z += __shfl_xor(acc.z, 32);
    acc.w += __shfl_xor(acc.w, 32);
    float4 bb = *(const float4*)(bias + fl * 4);
    acc.x = fmaf(dn, acc.x, bb.x);
    acc.y = fmaf(dn, acc.y, bb.y);
    acc.z = fmaf(dn, acc.z, bb.z);
    acc.w = fmaf(dn, acc.w, bb.w);
    if (relu) {
        acc.x = fmaxf(acc.x, 0.f); acc.y = fmaxf(acc.y, 0.f);
        acc.z = fmaxf(acc.z, 0.f); acc.w = fmaxf(acc.w, 0.f);
    }
    if (half == 0) {
        uint2 o;
        o.x = (unsigned)f2bf(acc.x) | ((unsigned)f2bf(acc.y) << 16);
        o.y = (unsigned)f2bf(acc.z) | ((unsigned)f2bf(acc.w) << 16);
        *(uint2*)(A + (size_t)n * HD + fl * 4) = o;
    }
}

// ---------------- graph bounds (batch is sorted) ----------------
__global__ void k_bounds(const int* __restrict__ batch, int* __restrict__ gstart,
                         int* __restrict__ gend) {
    int i = blockIdx.x * blockDim.x + threadIdx.x;
    if (i < NN) {
        int g = batch[i];
        atomicMin(&gstart[g], i);
        atomicMax(&gend[g], i + 1);
    }
}

// ------- mean pool per graph: 8 independent partial sums (8 loads in flight) -------
__global__ __launch_bounds__(128) void k_pool(const unsigned short* __restrict__ A,
                                              const int* __restrict__ gstart,
                                              const int* __restrict__ gend,
                                              float* __restrict__ out) {
    int g = blockIdx.x;
    int t = threadIdx.x;
    int s = gstart[g], e = gend[g];
    float acc[8];
#pragma unroll
    for (int q = 0; q < 8; ++q) acc[q] = 0.f;
    int cntn = 0;
    if (s < e) {
        cntn = e - s;
        int n = s;
        for (; n + 8 <= e; n += 8) {
#pragma unroll
            for (int q = 0; q < 8; ++q)
                acc[q] += bf2f(A[(size_t)(n + q) * HD + t]);
        }
        for (; n < e; ++n) acc[0] += bf2f(A[(size_t)n * HD + t]);
    }
    float tot = ((acc[0] + acc[1]) + (acc[2] + acc[3])) +
                ((acc[4] + acc[5]) + (acc[6] + acc[7]));
    out[(size_t)g * HD + t] = tot / fmaxf((float)cntn, 1.f);
}

extern "C" void kernel_launch(void* const* d_in, const int* in_sizes, int n_in,
                              void* d_out, int out_size, void* d_ws, size_t ws_size,
                              hipStream_t stream) {
    const int*   x     = (const int*)d_in[0];
    const int*   ei    = (const int*)d_in[1];
    const int*   batch = (const int*)d_in[2];
    const float* emb   = (const float*)d_in[3];
    const float* Ws    = (const float*)d_in[4];
    const float* bs    = (const float*)d_in[5];
    float* out = (float*)d_out;

    const int* srcE = ei;
    const int* dstE = ei + NE;

    char* ws = (char*)d_ws;
    size_t off = 0;
    auto alloc = [&](size_t bytes) {
        size_t o = off;
        off = (off + bytes + 255) & ~(size_t)255;
        return o;
    };
    unsigned short* hA  = (unsigned short*)(ws + alloc((size_t)NN * HD * 2));
    unsigned short* hB  = (unsigned short*)(ws + alloc((size_t)NN * HD * 2));
    unsigned short* WhT = (unsigned short*)(ws + alloc((size_t)NL * HD * HD * 2));
    unsigned short* WlT = (unsigned short*)(ws + alloc((size_t)NL * HD * HD * 2));
    float* dinv   = (float*)(ws + alloc((size_t)NN * 4));
    int*   cnt    = (int*)  (ws + alloc((size_t)NN * 4));
    int*   srcT   = (int*)  (ws + alloc((size_t)NN * CAP * 4));
    int*   gstart = (int*)  (ws + alloc((size_t)NG * 4));
    int*   gend   = (int*)  (ws + alloc((size_t)NG * 4));
    (void)ws_size; (void)in_sizes; (void)n_in; (void)out_size;

    k_init<<<(NN + 255) / 256, 256, 0, stream>>>(cnt, gstart, gend);
    {
        int chunks = (NE + 255) / 256;
        k_fillcap<<<chunks * NPARTS, 256, 0, stream>>>(srcE, dstE, cnt, srcT);
    }
    k_deg<<<(NN + 255) / 256, 256, 0, stream>>>(cnt, dinv);
    k_wprep<<<(NL * HD * HD + 255) / 256, 256, 0, stream>>>(Ws, WhT, WlT);

    const int GGRID = (NN + 63) / 64;
    for (int l = 0; l < NL; ++l) {
        size_t wo = (size_t)l * HD * HD;
        if (l == 0)
            k_gemm_mfma<1><<<GGRID, 256, 0, stream>>>(hA, x, emb, WhT + wo, WlT + wo, hB);
        else
            k_gemm_mfma<0><<<GGRID, 256, 0, stream>>>(hA, x, emb, WhT + wo, WlT + wo, hB);
        k_gather<<<(NN + 3) / 4, 256, 0, stream>>>(hB, cnt, srcT, dinv,
                                                   bs + (size_t)l * HD, hA,
                                                   (l < NL - 1) ? 1 : 0);
    }

    k_bounds<<<(NN + 255) / 256, 256, 0, stream>>>(batch, gstart, gend);
    k_pool<<<NG, 128, 0, stream>>>(hA, gstart, gend, out);
}